// Round 8
// baseline (532.729 us; speedup 1.0000x reference)
//
#include <hip/hip_runtime.h>
#include <stdint.h>

// ---------------------------------------------------------------------------
// SelfAttention (B=4, C=512, N=4096, A=512), softmax over QUERY axis (n).
// All-fp16 MFMA pipeline, z-batched.
//   prep:   weights -> fp16; x[b][c][n] -> xT[b][n][c] fp16
//   projQK: QK[z][n][0:512]=Q+bq, [512:1024]=K+bk          (fp16)
//   projV:  Vt[z][c][m] = Wv·x + bv                         (fp16)
//   scores: S~[z][n][m] = fp16 exp(s - tile_col_max), tile col max/sum stats
//   stats_scale: lse + fs16[z][tile][m] = fp16 exp(pmax - lse)  (fused)
//   gemm3:  out[z][n][c] = x.flat + 0.1 * sum_m (S~*fs16)[n][m] Vt[c][m]
//
// Staging modes (template STG) — r8 rethink: all prior schedule variants
// (drain-0 / dbuf / ring, depth 1-3) plateaued at 27-31% MfmaUtil. Budget
// analysis: 8 ds_read_b128 per 16 MFMA = 512 B LDS per MFMA slot ~= the
// LDS supply edge, plus 2 barriers per 78 cyc of MFMA issue. The MFMA
// fragment pattern read DIRECTLY from global is 16 fully-used 64B lines
// per instruction — LDS round-trip is only worth 2x reuse, which L2
// absorbs. So: skip LDS for cache-warm operands; engineer prefetch only
// for the one cold HBM stream (gemm3's S16).
//   STG=0: reg-staged LDS 2-barrier loop (projQK/projV — proven).
//   STG=3: LDS-free direct-fragment K-loop (scores): fa/fb straight from
//          global (QK is L2/L3-warm), no barriers, no staging, compiler
//          free-schedules. OCC=4.
//   STG=4: gemm3: A(S16)-only LDS ring NBUF=4 x KSTEP=64 (64 KB),
//          depth-3 counted vmcnt (~3 MFMA phases >= HBM ~900 cyc),
//          SINGLE barrier/iter (restage target was read at iter-1; the
//          entry barrier guarantees those reads landed in registers).
//          B(Vt, L2-warm) + fsv direct from global, issued BEFORE the
//          stage DMAs (+sched_barrier) so their compiler waits are
//          vmcnt(4) and never drain the prefetch.
//   DMA LDS layout: linear [128][32]/subtile; XOR slot swizzle on the
//   GLOBAL source (slot=(l&3)^((l>>3)&3)) + matching ds_read slot
//   (quad^((lrow>>1)&3)) — 0 bank conflicts (r2-measured).
// ---------------------------------------------------------------------------

#define LDT 40    // padded LDS row (f16 elems) per 32-k subtile (STG=0)
#define SUB 5120  // 128*LDT elems per subtile (STG=0)

typedef _Float16 f16x8 __attribute__((ext_vector_type(8)));
typedef float f32x4 __attribute__((ext_vector_type(4)));

__device__ __forceinline__ void async16(const _Float16* g, _Float16* l)
{
  __builtin_amdgcn_global_load_lds(
      (const __attribute__((address_space(1))) void*)g,
      (__attribute__((address_space(3))) void*)l, 16, 0, 0);
}

#define WVM(N) asm volatile("s_waitcnt vmcnt(" #N ")" ::: "memory")

// ASRC: 0 = plain A; 1 = A scaled by fs16[z][i0>>7][k] (gemm3)
// EPI:  1 = fp16 out + bias by col (bias0 j<512, bias1 else)  [projQK]
//       2 = fp16 out + bias by row (bias0)                     [projV]
//       3 = fp32 out = xadd[o] + alpha*acc                     [gemm3]
//       4 = fused scores: tile col stats -> pmax/psum, S~ fp16  [scores]
// NSUB: subtiles per phase (STG=0)
// OCC:  min waves/EU for __launch_bounds__
template <int ASRC, int EPI, int NSUB, int STG, int OCC>
__global__ void __launch_bounds__(256, OCC) gemm_f16(
    const _Float16* __restrict__ Ap, long lda, long zsa,
    const _Float16* __restrict__ Bp, long ldb, long zsb,
    int kslice,
    const _Float16* __restrict__ fs16, long zsl,
    float* __restrict__ outF, _Float16* __restrict__ outH, long ldc, long zso,
    const float* __restrict__ bias0, const float* __restrict__ bias1,
    const float* __restrict__ xadd,
    float* __restrict__ pmax, float* __restrict__ psum, long zsp,
    float alpha)
{
  constexpr int SMEM_E = (STG == 3) ? 4096            // epilogue scratch only
                       : (STG == 4) ? 32768           // 4 x 16 KB A ring
                                    : (2 * NSUB * SUB);
  __shared__ _Float16 smem[SMEM_E];

  const int z = blockIdx.z;
  const long i0 = (long)blockIdx.x * 128;
  const long j0 = (long)blockIdx.y * 128;
  const int t = (int)threadIdx.x;
  const int lane = t & 63;
  const int wv = t >> 6;
  const int quad = lane >> 4;
  const int lrow = lane & 15;
  const int wm = (wv & 1) << 6;
  const int wn = (wv >> 1) << 6;

  f32x4 acc[4][4];
  const f32x4 fz = {0.f, 0.f, 0.f, 0.f};
#pragma unroll
  for (int a = 0; a < 4; a++)
#pragma unroll
    for (int b = 0; b < 4; b++) acc[a][b] = fz;

  if constexpr (STG == 0) {
    // ---------- reg-staged path (coalesced lane map), 2-barrier ----------
    const int r0 = t >> 2;
    const int s0 = (t & 3) << 3;

    const _Float16* gA0 = Ap + z * zsa + (i0 + r0) * lda + s0;
    const _Float16* gA1 = gA0 + 64 * lda;
    const _Float16* gB0 = Bp + z * zsb + (j0 + r0) * ldb + s0;
    const _Float16* gB1 = gB0 + 64 * ldb;
    const int la0 = r0 * LDT + s0;
    const int la1 = (r0 + 64) * LDT + s0;

    for (int kk = 0; kk < kslice; kk += 32 * NSUB) {
      f16x8 va[NSUB][2], vb[NSUB][2];
#pragma unroll
      for (int s = 0; s < NSUB; s++) {
        va[s][0] = *(const f16x8*)(gA0 + kk + 32 * s);
        va[s][1] = *(const f16x8*)(gA1 + kk + 32 * s);
        vb[s][0] = *(const f16x8*)(gB0 + kk + 32 * s);
        vb[s][1] = *(const f16x8*)(gB1 + kk + 32 * s);
      }
      __syncthreads();
#pragma unroll
      for (int s = 0; s < NSUB; s++) {
        *(f16x8*)&smem[s * SUB + la0] = va[s][0];
        *(f16x8*)&smem[s * SUB + la1] = va[s][1];
        *(f16x8*)&smem[(NSUB + s) * SUB + la0] = vb[s][0];
        *(f16x8*)&smem[(NSUB + s) * SUB + la1] = vb[s][1];
      }
      __syncthreads();

#pragma unroll
      for (int h = 0; h < NSUB; h++) {
        const _Float16* pA = smem + h * SUB;
        const _Float16* pB = smem + (NSUB + h) * SUB;
        f16x8 fa[4], fb[4];
#pragma unroll
        for (int f = 0; f < 4; f++) {
          fa[f] = *(const f16x8*)&pA[(wm + f * 16 + lrow) * LDT + quad * 8];
          fb[f] = *(const f16x8*)&pB[(wn + f * 16 + lrow) * LDT + quad * 8];
        }
#pragma unroll
        for (int fm = 0; fm < 4; fm++)
#pragma unroll
          for (int fn = 0; fn < 4; fn++)
            acc[fm][fn] = __builtin_amdgcn_mfma_f32_16x16x32_f16(fa[fm], fb[fn], acc[fm][fn], 0, 0, 0);
      }
    }
  } else if constexpr (STG == 3) {
    // ---- LDS-free direct-fragment loop (cache-warm operands) ----
    // per lane: 16B at row (wm+f*16+lrow), cols kk+quad*8 — a wave covers
    // 16 rows x 64B = 16 fully-used cachelines per instruction.
    const _Float16* gA[4];
    const _Float16* gB[4];
#pragma unroll
    for (int f = 0; f < 4; f++) {
      gA[f] = Ap + z * zsa + (i0 + wm + f * 16 + lrow) * lda + quad * 8;
      gB[f] = Bp + z * zsb + (j0 + wn + f * 16 + lrow) * ldb + quad * 8;
    }
    for (int kk = 0; kk < kslice; kk += 32) {
      f16x8 fa[4], fb[4];
#pragma unroll
      for (int f = 0; f < 4; f++) {
        fa[f] = *(const f16x8*)(gA[f] + kk);
        fb[f] = *(const f16x8*)(gB[f] + kk);
      }
#pragma unroll
      for (int fm = 0; fm < 4; fm++)
#pragma unroll
        for (int fn = 0; fn < 4; fn++)
          acc[fm][fn] = __builtin_amdgcn_mfma_f32_16x16x32_f16(fa[fm], fb[fn], acc[fm][fn], 0, 0, 0);
    }
  } else {
    // ---- STG=4 (gemm3): A-ring depth-3 + direct B/fsv, 1 barrier/iter ----
    const int crow = lane >> 2;                               // row in 16-row chunk
    const int ks8 = (((lane & 3) ^ ((lane >> 3) & 3)) << 3);  // inverse-swizzled k slot

    const _Float16* gAc0 = Ap + z * zsa + (i0 + 16 * wv + crow) * lda + ks8;
    const _Float16* gAc1 = gAc0 + 64 * lda;

    const _Float16* gB[4];
#pragma unroll
    for (int f = 0; f < 4; f++)
      gB[f] = Bp + z * zsb + (j0 + wn + f * 16 + lrow) * ldb + quad * 8;

    const _Float16* fsZq = fs16 + z * zsl + (long)blockIdx.x * 4096 + quad * 8;

    // swizzled read slot: k-slice quad*8 sits at slot quad^((lrow>>1)&3)
    const int qs = ((quad ^ ((lrow >> 1) & 3)) << 3);

    // buffer = 64-k A tile (16 KB = 8192 f16), two 32-k subtiles of 4096
    auto stage = [&](int buf, int kk2) {
      _Float16* base = smem + buf * 8192;
      async16(gAc0 + kk2, base + wv * 512);
      async16(gAc1 + kk2, base + 2048 + wv * 512);
      async16(gAc0 + kk2 + 32, base + 4096 + wv * 512);
      async16(gAc1 + kk2 + 32, base + 4096 + 2048 + wv * 512);
    };

    stage(0, 0);
    stage(1, 64);
    stage(2, 128);  // 12 DMA outstanding; iter 0's WVM(8) drains stage(0)

    int ib = 0;
    for (int kk = 0; kk < kslice; kk += 64, ++ib) {
      const int rem = kslice - kk;  // uniform scalar branches
      // buf[ib] staged 3 iters ago; drain down to the newer stages only.
      if (rem > 128) { WVM(8); }
      else if (rem > 64) { WVM(4); }
      else { WVM(0); }
      __builtin_amdgcn_s_barrier();  // all waves' buf[ib] landed AND all
                                     // waves' iter ib-1 reads are in regs

      // direct loads first: their compiler waits are then vmcnt(4),
      // counting only the 4 stage DMAs issued below — never the ring.
      f16x8 fsv[2], fb[2][4];
#pragma unroll
      for (int h = 0; h < 2; h++) {
        fsv[h] = *(const f16x8*)(fsZq + kk + 32 * h);
#pragma unroll
        for (int f = 0; f < 4; f++)
          fb[h][f] = *(const f16x8*)(gB[f] + kk + 32 * h);
      }
      __builtin_amdgcn_sched_barrier(0);  // pin issue order: loads THEN stage
      if (rem > 192) stage((ib + 3) & 3, kk + 192);  // depth-3 prefetch

      const _Float16* pBuf = smem + (ib & 3) * 8192;
#pragma unroll
      for (int h = 0; h < 2; h++) {
        const _Float16* pA = pBuf + h * 4096;
        f16x8 fa[4];
#pragma unroll
        for (int f = 0; f < 4; f++) {
          fa[f] = *(const f16x8*)&pA[(wm + f * 16 + lrow) * 32 + qs];
          fa[f] = fa[f] * fsv[h];
        }
#pragma unroll
        for (int fm = 0; fm < 4; fm++)
#pragma unroll
          for (int fn = 0; fn < 4; fn++)
            acc[fm][fn] = __builtin_amdgcn_mfma_f32_16x16x32_f16(fa[fm], fb[h][fn], acc[fm][fn], 0, 0, 0);
      }
      // no trailing barrier: next iter's entry barrier provides the fence
    }
  }

  // D frag: col(j) = lane&15 (+wn+fn*16), row(i) = quad*4 + reg (+wm+fm*16)
  const long obase = (long)z * zso;

  if constexpr (EPI == 1 || EPI == 2) {
#pragma unroll
    for (int fm = 0; fm < 4; fm++) {
      const long gi0 = i0 + wm + fm * 16 + quad * 4;
#pragma unroll
      for (int fn = 0; fn < 4; fn++) {
        const long gj = j0 + wn + fn * 16 + lrow;
        float badd = 0.f;
        if constexpr (EPI == 1) badd = (gj < 512) ? bias0[gj] : bias1[gj - 512];
#pragma unroll
        for (int r = 0; r < 4; r++) {
          float v = acc[fm][fn][r];
          if constexpr (EPI == 1) v += badd;
          else v += bias0[gi0 + r];
          outH[obase + (gi0 + r) * ldc + gj] = (_Float16)v;
        }
      }
    }
  } else if constexpr (EPI == 3) {
#pragma unroll
    for (int fm = 0; fm < 4; fm++) {
      const long gi0 = i0 + wm + fm * 16 + quad * 4;
#pragma unroll
      for (int fn = 0; fn < 4; fn++) {
        const long gj = j0 + wn + fn * 16 + lrow;
#pragma unroll
        for (int r = 0; r < 4; r++) {
          const long o = obase + (gi0 + r) * ldc + gj;
          outF[o] = fmaf(alpha, acc[fm][fn][r], xadd[o]);
        }
      }
    }
  } else {  // EPI == 4: single-exp fused scores epilogue
    __syncthreads();
    float* Ls = (float*)smem;
    // LDS float layout: [0,1024) partials (max, then reused for sums)
    //                   [1024,1280) half-maxes, [1280,1408) Mcol
    // stage 1: per-lane per-column-group MAX only (no exp)
#pragma unroll
    for (int fn = 0; fn < 4; fn++) {
      float mx = -3.4e38f;
#pragma unroll
      for (int fm = 0; fm < 4; fm++)
#pragma unroll
        for (int r = 0; r < 4; r++) mx = fmaxf(mx, acc[fm][fn][r]);
      Ls[(wv * 4 + quad) * 64 + fn * 16 + lrow] = mx;
    }
    __syncthreads();
    // stage 2: combine 4 quads -> per (row-half h, col c) max
    {
      const int c = t & 127;
      const int h = t >> 7;
      const int wvv = ((c >> 6) << 1) + h;
      const int wc = c & 63;
      float M = -3.4e38f;
#pragma unroll
      for (int q = 0; q < 4; q++) M = fmaxf(M, Ls[(wvv * 4 + q) * 64 + wc]);
      Ls[1024 + h * 128 + c] = M;
    }
    __syncthreads();
    // stage 3: column max; store pmax; park Mcol in LDS
    if (t < 128) {
      float Mcol = fmaxf(Ls[1024 + t], Ls[1152 + t]);
      pmax[z * zsp + (long)blockIdx.x * 4096 + j0 + t] = Mcol;
      Ls[1280 + t] = Mcol;
    }
    __syncthreads();
    // stage 4: single exp pass — store S~ AND accumulate column partial sums
#pragma unroll
    for (int fn = 0; fn < 4; fn++) {
      const int colc = wn + fn * 16 + lrow;
      const float Mcol = Ls[1280 + colc];
      const long gj = j0 + colc;
      float sm = 0.f;
#pragma unroll
      for (int fm = 0; fm < 4; fm++) {
        const long gi0 = i0 + wm + fm * 16 + quad * 4;
#pragma unroll
        for (int r = 0; r < 4; r++) {
          float e = __expf(acc[fm][fn][r] - Mcol);
          sm += e;
          outH[obase + (gi0 + r) * ldc + gj] = (_Float16)e;
        }
      }
      Ls[(wv * 4 + quad) * 64 + fn * 16 + lrow] = sm;  // reuse partial region
    }
    __syncthreads();
    // stage 5: pure-add reduce of 8 partials per column -> psum
    if (t < 128) {
      const int wc = t & 63;
      const int ch = t >> 6;
      float s = 0.f;
#pragma unroll
      for (int h = 0; h < 2; h++) {
        const int wvv = (ch << 1) + h;
#pragma unroll
        for (int q = 0; q < 4; q++) s += Ls[(wvv * 4 + q) * 64 + wc];
      }
      psum[z * zsp + (long)blockIdx.x * 4096 + j0 + t] = s;
    }
  }
}

__global__ void convert_weights(const float* __restrict__ Wq, const float* __restrict__ Wk,
                                const float* __restrict__ Wv,
                                _Float16* __restrict__ WQK, _Float16* __restrict__ Wv16)
{
  int idx = blockIdx.x * 256 + threadIdx.x;  // 0..786431
  if (idx < 524288)
    WQK[idx] = (_Float16)((idx < 262144) ? Wq[idx] : Wk[idx - 262144]);
  else
    Wv16[idx - 524288] = (_Float16)Wv[idx - 524288];
}

// x [b][c][n] fp32 -> xT [b][n][c] fp16
__global__ void transpose_x(const float* __restrict__ x, _Float16* __restrict__ xT)
{
  __shared__ float tile[32][33];
  const int b = blockIdx.z;
  const int n0 = blockIdx.x * 32;
  const int c0 = blockIdx.y * 32;
  const int tx = threadIdx.x;
  const int ty = threadIdx.y;
  const float* xb = x + (long)b * 2097152;
#pragma unroll
  for (int k = 0; k < 4; k++)
    tile[ty + k * 8][tx] = xb[(long)(c0 + ty + k * 8) * 4096 + n0 + tx];
  __syncthreads();
  _Float16* xTb = xT + (long)b * 2097152;
#pragma unroll
  for (int k = 0; k < 4; k++)
    xTb[(long)(n0 + ty + k * 8) * 512 + c0 + tx] = (_Float16)tile[tx][ty + k * 8];
}

// fused: lse[z][m] from 32 tile partials, then fs16[z][tile][m] = exp(pmax-lse)
__global__ void stats_scale(const float* __restrict__ pmax, const float* __restrict__ psum,
                            _Float16* __restrict__ fs16)
{
  const int idx = blockIdx.x * 256 + threadIdx.x;  // grid 64: z*4096+m
  const int z = idx >> 12;
  const int m = idx & 4095;
  const float* pm = pmax + (long)z * 131072 + m;
  const float* ps = psum + (long)z * 131072 + m;
  float M = -3.4e38f, S = 0.f;
  for (int i = 0; i < 32; i++) {
    float m2 = pm[(long)i * 4096], s2 = ps[(long)i * 4096];
    float nm = fmaxf(M, m2);
    S = S * __expf(M - nm) + s2 * __expf(m2 - nm);
    M = nm;
  }
  const float lse = M + __logf(S);
  _Float16* fo = fs16 + (long)z * 131072 + m;
  for (int i = 0; i < 32; i++)
    fo[(long)i * 4096] = (_Float16)__expf(pm[(long)i * 4096] - lse);
}

extern "C" void kernel_launch(void* const* d_in, const int* in_sizes, int n_in,
                              void* d_out, int out_size, void* d_ws, size_t ws_size,
                              hipStream_t stream)
{
  const float* x  = (const float*)d_in[0];
  const float* Wq = (const float*)d_in[1];
  const float* bq = (const float*)d_in[2];
  const float* Wk = (const float*)d_in[3];
  const float* bk = (const float*)d_in[4];
  const float* Wv = (const float*)d_in[5];
  const float* bv = (const float*)d_in[6];
  float* out = (float*)d_out;

  char* w = (char*)d_ws;
  _Float16* WQK   = (_Float16*)(w + 0);          //  1,048,576
  _Float16* Wv16  = (_Float16*)(w + 1048576);    //    524,288
  _Float16* xT    = (_Float16*)(w + 1572864);    // 16,777,216
  _Float16* QK    = (_Float16*)(w + 18350080);   // 33,554,432
  _Float16* Vt    = (_Float16*)(w + 51904512);   // 16,777,216
  float*    pmaxB = (float*)   (w + 68747264);   //  2,097,152
  float*    psumB = (float*)   (w + 70844416);   //  2,097,152
  _Float16* fs16  = (_Float16*)(w + 72941568);   //  1,048,576 = [z][32][4096] fp16
  _Float16* S16   = (_Float16*)(w + 75038720);   // 134,217,728
  // total 209,256,448 B

  convert_weights<<<3072, 256, 0, stream>>>(Wq, Wk, Wv, WQK, Wv16);
  transpose_x<<<dim3(128, 16, 4), dim3(32, 8), 0, stream>>>(x, xT);

  // projQK (STG=0, proven): QK[z][n][j], j<512 Q(+bq) else K(+bk)
  gemm_f16<0, 1, 2, 0, 2><<<dim3(32, 8, 4), 256, 0, stream>>>(
      xT, 512, 2097152L, WQK, 512, 0L, 512, nullptr, 0L,
      nullptr, QK, 1024, 4194304L, bq, bk, nullptr, nullptr, nullptr, 0L, 0.f);
  // projV (STG=0, proven): Vt[z][c][m] fp16 (+bv by row)
  gemm_f16<0, 2, 2, 0, 2><<<dim3(4, 32, 4), 256, 0, stream>>>(
      Wv16, 512, 0L, xT, 512, 2097152L, 512, nullptr, 0L,
      nullptr, Vt, 4096, 2097152L, bv, nullptr, nullptr, nullptr, nullptr, 0L, 0.f);
  // scores (STG=3 direct-fragment, no LDS/barriers in K-loop):
  gemm_f16<0, 4, 2, 3, 4><<<dim3(32, 32, 4), 256, 0, stream>>>(
      QK, 1024, 4194304L, QK + 512, 1024, 4194304L, 512, nullptr, 0L,
      nullptr, S16, 4096, 16777216L, nullptr, nullptr, nullptr,
      pmaxB, psumB, 131072L, 0.f);
  stats_scale<<<64, 256, 0, stream>>>(pmaxB, psumB, fs16);
  // gemm3 (STG=4: A-ring depth-3 counted vmcnt + direct B/fsv, 64 KB):
  // out = x.flat + 0.1*(S~*fs16)·Vt^T
  gemm_f16<1, 3, 2, 4, 2><<<dim3(32, 4, 4), 256, 0, stream>>>(
      S16, 4096, 16777216L, Vt, 4096, 2097152L, 4096, fs16, 131072L,
      out, nullptr, 512, 2097152L, nullptr, nullptr, x, nullptr, nullptr, 0L, 0.1f);
}

// Round 10
// 336.934 us; speedup vs baseline: 1.5811x; 1.5811x over previous
//
#include <hip/hip_runtime.h>
#include <stdint.h>

// ---------------------------------------------------------------------------
// SelfAttention (B=4, C=512, N=4096, A=512), softmax over QUERY axis (n).
// All-fp16 MFMA pipeline, z-batched.
//   prep:   weights -> fp16; x[b][c][n] -> xT[b][n][c] fp16
//   projQK: QK[z][n][0:512]=Q+bq, [512:1024]=K+bk          (fp16)
//   projV:  Vt[z][c][m] = Wv·x + bv                         (fp16)
//   scores256: S~[z][n][m] fp16 + 256-row-tile col stats    (8-phase 256²)
//   stats_scale: lse + fs16[z][16][m] = exp(pmax - lse)      (fused)
//   gemm3:  out[z][n][c] = x.flat + 0.1 * sum_m (S~*fs16)[n][m] Vt[c][m]
//
// r9 post-mortem: NaN came from a staging address bug — the stage lambda
// used wv*256 for the wave's LDS slice, but 16 rows x 32 f16 = 512 f16:
// wave slices overlapped and rows 72-127 of every subtile were never
// written (uninitialized LDS -> NaN). Fixed to wv*512 (matches the proven
// 128² DMA kernels). Pipeline/vmcnt logic re-audited clean.
//
// scores256 = port of the 256² 8-wave 8-phase schedule (T3+T4+T5):
// per BK=64 K-tile, 4 phases of {ds_read subtile; stage 1 chunk (2 DMA);
// barrier; setprio(1); 16 MFMA; setprio(0); barrier}; staging order
// Bk0->Ak0->Bk1->Ak1 targets regions freed exactly one phase earlier;
// ONE counted vmcnt(6) per K-tile (3 chunks in flight). LDS 128 KB dbuf,
// linear [128][32] subtiles + XOR slot swizzle on the global source
// (slot=(l&3)^((l>>3)&3)) + matching read slot (quad^((lrow>>1)&3)) —
// 0 bank conflicts (r2-measured).
// ---------------------------------------------------------------------------

#define LDT 40    // padded LDS row (f16 elems) per 32-k subtile (STG=0)
#define SUB 5120  // 128*LDT elems per subtile (STG=0)

typedef _Float16 f16x8 __attribute__((ext_vector_type(8)));
typedef float f32x4 __attribute__((ext_vector_type(4)));

__device__ __forceinline__ void async16(const _Float16* g, _Float16* l)
{
  __builtin_amdgcn_global_load_lds(
      (const __attribute__((address_space(1))) void*)g,
      (__attribute__((address_space(3))) void*)l, 16, 0, 0);
}

#define WVM(N) asm volatile("s_waitcnt vmcnt(" #N ")" ::: "memory")

// ============================ scores256 =====================================
// C[n][m] tile 256x256, A=Q rows (lda 1024), B=K rows (ldb 1024), K=512.
// 8 waves: wr=wv>>2 (row half), wc=wv&3 (col quarter); wave tile 128x64,
// acc[8][4]. Grid (16,16,4), 512 threads, 1 block/CU (128 KB LDS).
__global__ void __launch_bounds__(512, 2) scores256(
    const _Float16* __restrict__ QKp, _Float16* __restrict__ S16,
    float* __restrict__ pmax, float* __restrict__ psum)
{
  __shared__ _Float16 smem[65536];  // 128 KB: 2 bufs x (A 16K f16 + B 16K f16)

  const int z = blockIdx.z;
  const long i0 = (long)blockIdx.x * 256;
  const long j0 = (long)blockIdx.y * 256;
  const int t = (int)threadIdx.x;  // 0..511
  const int lane = t & 63;
  const int wv = t >> 6;           // 0..7
  const int quad = lane >> 4;
  const int lrow = lane & 15;
  const int wr = wv >> 2;          // 0..1
  const int wc = wv & 3;           // 0..3
  const int wm = wr << 7;
  const int wn = wc << 6;

  const _Float16* Qz = QKp + (long)z * 4194304;        // queries (rows n)
  const _Float16* Kz = QKp + 512 + (long)z * 4194304;  // keys (rows m)

  // staging: chunk (isB, kh) = 2 subtiles (rh=0,1) of [128][32]; per wave
  // rows 16wv..16wv+15; lane -> row 16wv+(lane>>2), phys slot lane&3 holds
  // logical k-slot (lane&3)^((lane>>3)&3) (inverse swizzle on global col).
  const int crow = lane >> 2;
  const int ks8 = (((lane & 3) ^ ((lane >> 3) & 3)) << 3);
  const _Float16* gQ = Qz + (i0 + wv * 16 + crow) * 1024 + ks8;
  const _Float16* gK = Kz + (j0 + wv * 16 + crow) * 1024 + ks8;

  // LDS (f16 idx): buf*32768 + isB*16384 + rh*8192 + kh*4096 + row*32 + slot
  // wave slice = 16 rows x 32 f16 = 512 f16 -> base offset wv*512 (r9 bug
  // was wv*256: overlapping slices + unwritten rows -> NaN).
  auto stage = [&](int buf, int kt2, int isB, int kh) {
    const _Float16* src = isB ? gK : gQ;
    const long col = (long)kt2 * 64 + kh * 32;
    _Float16* d = smem + buf * 32768 + isB * 16384 + kh * 4096 + wv * 512;
    async16(src + col, d);                       // rh=0
    async16(src + col + 128 * 1024, d + 8192);   // rh=1
  };

  // fragment read: logical k-slice quad*8 at phys slot quad^((lrow>>1)&3)
  const int qs = ((quad ^ ((lrow >> 1) & 3)) << 3);

  f32x4 acc[8][4];
  const f32x4 fz = {0.f, 0.f, 0.f, 0.f};
#pragma unroll
  for (int a = 0; a < 8; a++)
#pragma unroll
    for (int b = 0; b < 4; b++) acc[a][b] = fz;

  // prologue: kt0 all 4 chunks -> buf0; kt1 Bk0,Ak0,Bk1 -> buf1 (Ak1(1)
  // staged at kt0 p0). 14 loads out; WVM(6) keeps kt1's 3 chunks in flight.
  stage(0, 0, 1, 0); stage(0, 0, 0, 0); stage(0, 0, 1, 1); stage(0, 0, 0, 1);
  stage(1, 1, 1, 0); stage(1, 1, 0, 0); stage(1, 1, 1, 1);
  WVM(6);
  __builtin_amdgcn_s_barrier();

  for (int kt = 0; kt < 8; ++kt) {
    const int buf = kt & 1;
    const _Float16* pA = smem + buf * 32768 + wr * 8192;
    const _Float16* pB = smem + buf * 32768 + 16384 + (wc >> 1) * 8192 + (wc & 1) * 2048;
    f16x8 fa[4], fb[4];

    // -------- phase 0: read A[m0,k0]+B[:,k0]; stage Ak1(kt+1) --------
#pragma unroll
    for (int f = 0; f < 4; f++) {
      fa[f] = *(const f16x8*)&pA[(f * 16 + lrow) * 32 + qs];
      fb[f] = *(const f16x8*)&pB[(f * 16 + lrow) * 32 + qs];
    }
    if (kt + 1 < 8) stage(buf ^ 1, kt + 1, 0, 1);
    __builtin_amdgcn_s_barrier();
    __builtin_amdgcn_sched_barrier(0);
    __builtin_amdgcn_s_setprio(1);
#pragma unroll
    for (int fm = 0; fm < 4; fm++)
#pragma unroll
      for (int fn = 0; fn < 4; fn++)
        acc[fm][fn] = __builtin_amdgcn_mfma_f32_16x16x32_f16(fa[fm], fb[fn], acc[fm][fn], 0, 0, 0);
    __builtin_amdgcn_s_setprio(0);
    __builtin_amdgcn_sched_barrier(0);
    __builtin_amdgcn_s_barrier();

    // -------- phase 1: read A[m1,k0]; stage Bk0(kt+2) (freed in p0) --------
#pragma unroll
    for (int f = 0; f < 4; f++)
      fa[f] = *(const f16x8*)&pA[((f + 4) * 16 + lrow) * 32 + qs];
    if (kt + 2 < 8) stage(buf, kt + 2, 1, 0);
    __builtin_amdgcn_s_barrier();
    __builtin_amdgcn_sched_barrier(0);
    __builtin_amdgcn_s_setprio(1);
#pragma unroll
    for (int fm = 0; fm < 4; fm++)
#pragma unroll
      for (int fn = 0; fn < 4; fn++)
        acc[4 + fm][fn] = __builtin_amdgcn_mfma_f32_16x16x32_f16(fa[fm], fb[fn], acc[4 + fm][fn], 0, 0, 0);
    __builtin_amdgcn_s_setprio(0);
    __builtin_amdgcn_sched_barrier(0);
    __builtin_amdgcn_s_barrier();

    // -------- phase 2: read A[m0,k1]+B[:,k1]; stage Ak0(kt+2) --------
#pragma unroll
    for (int f = 0; f < 4; f++) {
      fa[f] = *(const f16x8*)&pA[4096 + (f * 16 + lrow) * 32 + qs];
      fb[f] = *(const f16x8*)&pB[4096 + (f * 16 + lrow) * 32 + qs];
    }
    if (kt + 2 < 8) stage(buf, kt + 2, 0, 0);
    __builtin_amdgcn_s_barrier();
    __builtin_amdgcn_sched_barrier(0);
    __builtin_amdgcn_s_setprio(1);
#pragma unroll
    for (int fm = 0; fm < 4; fm++)
#pragma unroll
      for (int fn = 0; fn < 4; fn++)
        acc[fm][fn] = __builtin_amdgcn_mfma_f32_16x16x32_f16(fa[fm], fb[fn], acc[fm][fn], 0, 0, 0);
    __builtin_amdgcn_s_setprio(0);
    __builtin_amdgcn_sched_barrier(0);
    __builtin_amdgcn_s_barrier();

    // -------- phase 3: read A[m1,k1]; stage Bk1(kt+2); vmcnt guard --------
#pragma unroll
    for (int f = 0; f < 4; f++)
      fa[f] = *(const f16x8*)&pA[4096 + ((f + 4) * 16 + lrow) * 32 + qs];
    if (kt + 2 < 8) stage(buf, kt + 2, 1, 1);
    // guard kt+1's 4 chunks: newer = kt+2's 3 chunks (6 loads) -> WVM(6)
    if (kt + 2 < 8) { WVM(6); }
    else if (kt + 1 < 8) { WVM(0); }  // kt=6: nothing staged after Ak1(7)
    __builtin_amdgcn_s_barrier();
    __builtin_amdgcn_sched_barrier(0);
    __builtin_amdgcn_s_setprio(1);
#pragma unroll
    for (int fm = 0; fm < 4; fm++)
#pragma unroll
      for (int fn = 0; fn < 4; fn++)
        acc[4 + fm][fn] = __builtin_amdgcn_mfma_f32_16x16x32_f16(fa[fm], fb[fn], acc[4 + fm][fn], 0, 0, 0);
    __builtin_amdgcn_s_setprio(0);
    __builtin_amdgcn_sched_barrier(0);
    __builtin_amdgcn_s_barrier();
  }

  // ---- epilogue: 256-col tile stats + single-exp S~ store ----
  // D frag: col = lane&15 (+wn+fn*16), row = quad*4+reg (+wm+fm*16)
  __syncthreads();
  float* Ls = (float*)smem;  // [0,2048) partials (8 per col), [2048,2304) Mcol
  const long obase = (long)z * 16777216;
#pragma unroll
  for (int fn = 0; fn < 4; fn++) {
    float mx = -3.4e38f;
#pragma unroll
    for (int fm = 0; fm < 8; fm++)
#pragma unroll
      for (int r = 0; r < 4; r++) mx = fmaxf(mx, acc[fm][fn][r]);
    Ls[(wr * 4 + quad) * 256 + wn + fn * 16 + lrow] = mx;
  }
  __syncthreads();
  if (t < 256) {
    float M = -3.4e38f;
#pragma unroll
    for (int p = 0; p < 8; p++) M = fmaxf(M, Ls[p * 256 + t]);
    pmax[(long)z * 65536 + (long)blockIdx.x * 4096 + j0 + t] = M;
    Ls[2048 + t] = M;
  }
  __syncthreads();
#pragma unroll
  for (int fn = 0; fn < 4; fn++) {
    const int colc = wn + fn * 16 + lrow;
    const float Mcol = Ls[2048 + colc];
    const long gj = j0 + colc;
    float sm = 0.f;
#pragma unroll
    for (int fm = 0; fm < 8; fm++) {
      const long gi0 = i0 + wm + fm * 16 + quad * 4;
#pragma unroll
      for (int r = 0; r < 4; r++) {
        float e = __expf(acc[fm][fn][r] - Mcol);
        sm += e;
        S16[obase + (gi0 + r) * 4096 + gj] = (_Float16)e;
      }
    }
    Ls[(wr * 4 + quad) * 256 + colc] = sm;  // reuse partial region
  }
  __syncthreads();
  if (t < 256) {
    float s = 0.f;
#pragma unroll
    for (int p = 0; p < 8; p++) s += Ls[p * 256 + t];
    psum[(long)z * 65536 + (long)blockIdx.x * 4096 + j0 + t] = s;
  }
}

// ===================== generic 128² GEMM (proj + gemm3) =====================
// ASRC: 0 = plain A; 1 = A scaled by fs16[z][i0>>8][k] (gemm3)
// EPI:  1 = fp16 out + bias by col (bias0 j<512, bias1 else)  [projQK]
//       2 = fp16 out + bias by row (bias0)                     [projV]
//       3 = fp32 out = xadd[o] + alpha*acc                     [gemm3]
// NSUB: subtiles per phase (STG=0) / K-chunks per buffer (STG=2)
template <int ASRC, int EPI, int NSUB, int STG, int OCC>
__global__ void __launch_bounds__(256, OCC) gemm_f16(
    const _Float16* __restrict__ Ap, long lda, long zsa,
    const _Float16* __restrict__ Bp, long ldb, long zsb,
    int kslice,
    const _Float16* __restrict__ fs16, long zsl,
    float* __restrict__ outF, _Float16* __restrict__ outH, long ldc, long zso,
    const float* __restrict__ bias0, const float* __restrict__ bias1,
    const float* __restrict__ xadd, float alpha)
{
  constexpr int SMEM_E = (STG == 2) ? (4 * NSUB * 4096) : (2 * NSUB * SUB);
  __shared__ _Float16 smem[SMEM_E];

  const int z = blockIdx.z;
  const long i0 = (long)blockIdx.x * 128;
  const long j0 = (long)blockIdx.y * 128;
  const int t = (int)threadIdx.x;
  const int lane = t & 63;
  const int wv = t >> 6;
  const int quad = lane >> 4;
  const int lrow = lane & 15;
  const int wm = (wv & 1) << 6;
  const int wn = (wv >> 1) << 6;

  f32x4 acc[4][4];
  const f32x4 fz = {0.f, 0.f, 0.f, 0.f};
#pragma unroll
  for (int a = 0; a < 4; a++)
#pragma unroll
    for (int b = 0; b < 4; b++) acc[a][b] = fz;

  if constexpr (STG == 0) {
    // ---------- reg-staged path (coalesced lane map), 2-barrier ----------
    const int r0 = t >> 2;
    const int s0 = (t & 3) << 3;

    const _Float16* gA0 = Ap + z * zsa + (i0 + r0) * lda + s0;
    const _Float16* gA1 = gA0 + 64 * lda;
    const _Float16* gB0 = Bp + z * zsb + (j0 + r0) * ldb + s0;
    const _Float16* gB1 = gB0 + 64 * ldb;
    const int la0 = r0 * LDT + s0;
    const int la1 = (r0 + 64) * LDT + s0;

    for (int kk = 0; kk < kslice; kk += 32 * NSUB) {
      f16x8 va[NSUB][2], vb[NSUB][2];
#pragma unroll
      for (int s = 0; s < NSUB; s++) {
        va[s][0] = *(const f16x8*)(gA0 + kk + 32 * s);
        va[s][1] = *(const f16x8*)(gA1 + kk + 32 * s);
        vb[s][0] = *(const f16x8*)(gB0 + kk + 32 * s);
        vb[s][1] = *(const f16x8*)(gB1 + kk + 32 * s);
      }
      __syncthreads();
#pragma unroll
      for (int s = 0; s < NSUB; s++) {
        *(f16x8*)&smem[s * SUB + la0] = va[s][0];
        *(f16x8*)&smem[s * SUB + la1] = va[s][1];
        *(f16x8*)&smem[(NSUB + s) * SUB + la0] = vb[s][0];
        *(f16x8*)&smem[(NSUB + s) * SUB + la1] = vb[s][1];
      }
      __syncthreads();

#pragma unroll
      for (int h = 0; h < NSUB; h++) {
        const _Float16* pA = smem + h * SUB;
        const _Float16* pB = smem + (NSUB + h) * SUB;
        f16x8 fa[4], fb[4];
#pragma unroll
        for (int f = 0; f < 4; f++) {
          fa[f] = *(const f16x8*)&pA[(wm + f * 16 + lrow) * LDT + quad * 8];
          fb[f] = *(const f16x8*)&pB[(wn + f * 16 + lrow) * LDT + quad * 8];
        }
#pragma unroll
        for (int fm = 0; fm < 4; fm++)
#pragma unroll
          for (int fn = 0; fn < 4; fn++)
            acc[fm][fn] = __builtin_amdgcn_mfma_f32_16x16x32_f16(fa[fm], fb[fn], acc[fm][fn], 0, 0, 0);
      }
    }
  } else {
    // ---- STG=2: DMA dbuf, KSTEP=64, 32-MFMA phases, vmcnt(8) ----
    constexpr int KSTEP = 32 * NSUB;
    constexpr int BUFE = 2 * NSUB * 4096;
    const int crow = lane >> 2;
    const int ks8 = (((lane & 3) ^ ((lane >> 3) & 3)) << 3);

    const _Float16* gAc0 = Ap + z * zsa + (i0 + 16 * wv + crow) * lda + ks8;
    const _Float16* gAc1 = gAc0 + 64 * lda;
    const _Float16* gBc0 = Bp + z * zsb + (j0 + 16 * wv + crow) * ldb + ks8;
    const _Float16* gBc1 = gBc0 + 64 * ldb;
    _Float16* ldsC0 = smem + wv * 512;
    _Float16* ldsC1 = smem + (wv + 4) * 512;

    const _Float16* fsZq = nullptr;
    if constexpr (ASRC == 1)  // scores tiles are 256 rows -> tile = bx>>1
      fsZq = fs16 + z * zsl + (long)(blockIdx.x >> 1) * 4096 + quad * 8;

    const int qs = ((quad ^ ((lrow >> 1) & 3)) << 3);

    auto stage = [&](int buf, int kk) {
#pragma unroll
      for (int s = 0; s < NSUB; s++) {
        const int ab = buf * BUFE + s * 4096;
        const int bb = buf * BUFE + (NSUB + s) * 4096;
        async16(gAc0 + kk + 32 * s, ldsC0 + ab);
        async16(gAc1 + kk + 32 * s, ldsC1 + ab);
        async16(gBc0 + kk + 32 * s, ldsC0 + bb);
        async16(gBc1 + kk + 32 * s, ldsC1 + bb);
      }
    };

    stage(0, 0);
    int cur = 0;
    for (int kk = 0; kk < kslice; kk += KSTEP) {
      f16x8 fsv[NSUB];
      if constexpr (ASRC == 1) {
#pragma unroll
        for (int h = 0; h < NSUB; h++)
          fsv[h] = *(const f16x8*)(fsZq + kk + 32 * h);
      }
      if (kk + KSTEP < kslice) {
        stage(cur ^ 1, kk + KSTEP);
        WVM(8);
      } else {
        WVM(0);
      }
      __builtin_amdgcn_s_barrier();

#pragma unroll
      for (int h = 0; h < NSUB; h++) {
        const _Float16* pA = smem + cur * BUFE + h * 4096;
        const _Float16* pB = smem + cur * BUFE + (NSUB + h) * 4096;
        f16x8 fa[4], fb[4];
#pragma unroll
        for (int f = 0; f < 4; f++) {
          fa[f] = *(const f16x8*)&pA[(wm + f * 16 + lrow) * 32 + qs];
          fb[f] = *(const f16x8*)&pB[(wn + f * 16 + lrow) * 32 + qs];
        }
        if constexpr (ASRC == 1) {
#pragma unroll
          for (int f = 0; f < 4; f++) fa[f] = fa[f] * fsv[h];
        }
#pragma unroll
        for (int fm = 0; fm < 4; fm++)
#pragma unroll
          for (int fn = 0; fn < 4; fn++)
            acc[fm][fn] = __builtin_amdgcn_mfma_f32_16x16x32_f16(fa[fm], fb[fn], acc[fm][fn], 0, 0, 0);
      }
      __builtin_amdgcn_s_barrier();
      cur ^= 1;
    }
  }

  // D frag: col(j) = lane&15 (+wn+fn*16), row(i) = quad*4 + reg (+wm+fm*16)
  const long obase = (long)z * zso;

  if constexpr (EPI == 1 || EPI == 2) {
#pragma unroll
    for (int fm = 0; fm < 4; fm++) {
      const long gi0 = i0 + wm + fm * 16 + quad * 4;
#pragma unroll
      for (int fn = 0; fn < 4; fn++) {
        const long gj = j0 + wn + fn * 16 + lrow;
        float badd = 0.f;
        if constexpr (EPI == 1) badd = (gj < 512) ? bias0[gj] : bias1[gj - 512];
#pragma unroll
        for (int r = 0; r < 4; r++) {
          float v = acc[fm][fn][r];
          if constexpr (EPI == 1) v += badd;
          else v += bias0[gi0 + r];
          outH[obase + (gi0 + r) * ldc + gj] = (_Float16)v;
        }
      }
    }
  } else {  // EPI == 3
#pragma unroll
    for (int fm = 0; fm < 4; fm++) {
      const long gi0 = i0 + wm + fm * 16 + quad * 4;
#pragma unroll
      for (int fn = 0; fn < 4; fn++) {
        const long gj = j0 + wn + fn * 16 + lrow;
#pragma unroll
        for (int r = 0; r < 4; r++) {
          const long o = obase + (gi0 + r) * ldc + gj;
          outF[o] = fmaf(alpha, acc[fm][fn][r], xadd[o]);
        }
      }
    }
  }
}

__global__ void convert_weights(const float* __restrict__ Wq, const float* __restrict__ Wk,
                                const float* __restrict__ Wv,
                                _Float16* __restrict__ WQK, _Float16* __restrict__ Wv16)
{
  int idx = blockIdx.x * 256 + threadIdx.x;  // 0..786431
  if (idx < 524288)
    WQK[idx] = (_Float16)((idx < 262144) ? Wq[idx] : Wk[idx - 262144]);
  else
    Wv16[idx - 524288] = (_Float16)Wv[idx - 524288];
}

// x [b][c][n] fp32 -> xT [b][n][c] fp16
__global__ void transpose_x(const float* __restrict__ x, _Float16* __restrict__ xT)
{
  __shared__ float tile[32][33];
  const int b = blockIdx.z;
  const int n0 = blockIdx.x * 32;
  const int c0 = blockIdx.y * 32;
  const int tx = threadIdx.x;
  const int ty = threadIdx.y;
  const float* xb = x + (long)b * 2097152;
#pragma unroll
  for (int k = 0; k < 4; k++)
    tile[ty + k * 8][tx] = xb[(long)(c0 + ty + k * 8) * 4096 + n0 + tx];
  __syncthreads();
  _Float16* xTb = xT + (long)b * 2097152;
#pragma unroll
  for (int k = 0; k < 4; k++)
    xTb[(long)(n0 + ty + k * 8) * 512 + c0 + tx] = (_Float16)tile[tx][ty + k * 8];
}

// fused: lse[z][m] from 16 tile partials, then fs16[z][tile][m] = exp(pmax-lse)
__global__ void stats_scale(const float* __restrict__ pmax, const float* __restrict__ psum,
                            _Float16* __restrict__ fs16)
{
  const int idx = blockIdx.x * 256 + threadIdx.x;  // grid 64: z*4096+m
  const int z = idx >> 12;
  const int m = idx & 4095;
  const float* pm = pmax + (long)z * 65536 + m;
  const float* ps = psum + (long)z * 65536 + m;
  float M = -3.4e38f, S = 0.f;
  for (int i = 0; i < 16; i++) {
    float m2 = pm[(long)i * 4096], s2 = ps[(long)i * 4096];
    float nm = fmaxf(M, m2);
    S = S * __expf(M - nm) + s2 * __expf(m2 - nm);
    M = nm;
  }
  const float lse = M + __logf(S);
  _Float16* fo = fs16 + (long)z * 65536 + m;
  for (int i = 0; i < 16; i++)
    fo[(long)i * 4096] = (_Float16)__expf(pm[(long)i * 4096] - lse);
}

extern "C" void kernel_launch(void* const* d_in, const int* in_sizes, int n_in,
                              void* d_out, int out_size, void* d_ws, size_t ws_size,
                              hipStream_t stream)
{
  const float* x  = (const float*)d_in[0];
  const float* Wq = (const float*)d_in[1];
  const float* bq = (const float*)d_in[2];
  const float* Wk = (const float*)d_in[3];
  const float* bk = (const float*)d_in[4];
  const float* Wv = (const float*)d_in[5];
  const float* bv = (const float*)d_in[6];
  float* out = (float*)d_out;

  char* w = (char*)d_ws;
  _Float16* WQK   = (_Float16*)(w + 0);          //  1,048,576
  _Float16* Wv16  = (_Float16*)(w + 1048576);    //    524,288
  _Float16* xT    = (_Float16*)(w + 1572864);    // 16,777,216
  _Float16* QK    = (_Float16*)(w + 18350080);   // 33,554,432
  _Float16* Vt    = (_Float16*)(w + 51904512);   // 16,777,216
  float*    pmaxB = (float*)   (w + 68747264);   //  1,048,576 used ([z][16][4096])
  float*    psumB = (float*)   (w + 70844416);   //  1,048,576 used
  _Float16* fs16  = (_Float16*)(w + 72941568);   //    524,288 used = [z][16][4096] fp16
  _Float16* S16   = (_Float16*)(w + 75038720);   // 134,217,728
  // total 209,256,448 B

  convert_weights<<<3072, 256, 0, stream>>>(Wq, Wk, Wv, WQK, Wv16);
  transpose_x<<<dim3(128, 16, 4), dim3(32, 8), 0, stream>>>(x, xT);

  // projQK (STG=0, proven): QK[z][n][j], j<512 Q(+bq) else K(+bk)
  gemm_f16<0, 1, 2, 0, 2><<<dim3(32, 8, 4), 256, 0, stream>>>(
      xT, 512, 2097152L, WQK, 512, 0L, 512, nullptr, 0L,
      nullptr, QK, 1024, 4194304L, bq, bk, nullptr, 0.f);
  // projV (STG=0, proven): Vt[z][c][m] fp16 (+bv by row)
  gemm_f16<0, 2, 2, 0, 2><<<dim3(4, 32, 4), 256, 0, stream>>>(
      Wv16, 512, 0L, xT, 512, 2097152L, 512, nullptr, 0L,
      nullptr, Vt, 4096, 2097152L, bv, nullptr, nullptr, 0.f);
  // scores256 (8-phase 256², 512 thr, 128 KB LDS): S~ + 16-tile col stats
  scores256<<<dim3(16, 16, 4), 512, 0, stream>>>(QK, S16, pmaxB, psumB);
  stats_scale<<<64, 256, 0, stream>>>(pmaxB, psumB, fs16);
  // gemm3 (STG=2 dbuf KSTEP=64, vmcnt(8), 64 KB — r4/r7-measured ~95):
  // out = x.flat + 0.1*(S~*fs16)·Vt^T  (fs tile = bx>>1, zsl 65536)
  gemm_f16<1, 3, 2, 2, 2><<<dim3(32, 4, 4), 256, 0, stream>>>(
      S16, 4096, 16777216L, Vt, 4096, 2097152L, 4096, fs16, 65536L,
      out, nullptr, 512, 2097152L, nullptr, nullptr, x, 0.1f);
}

// Round 11
// 315.979 us; speedup vs baseline: 1.6860x; 1.0663x over previous
//
#include <hip/hip_runtime.h>
#include <stdint.h>

// ---------------------------------------------------------------------------
// SelfAttention (B=4, C=512, N=4096, A=512), softmax over QUERY axis (n).
// All-fp16 MFMA pipeline, z-batched.
//   prep:   weights -> fp16; x[b][c][n] -> xT[b][n][c] fp16
//   projQK: QK[z][n][0:512]=Q+bq, [512:1024]=K+bk          (fp16)
//   projV:  Vt[z][c][m] = Wv·x + bv                         (fp16)
//   scores: S~[z][n][m] = fp16 exp(s - tile_col_max), tile col max/sum stats
//   stats_scale: lse + fs16[z][32][m] = exp(pmax - lse)      (fused)
//   gemm3:  out[z][n][c] = x.flat + 0.1 * sum_m (S~*fs16)[n][m] Vt[c][m]
//
// FINAL CONFIG (r11 = r7 revert, measured-best per component):
//   STG=0: reg-staged LDS 2-barrier loop, 32-MFMA phases, 40 KB.
//          projQK/projV (r6: the KSTEP=32 ring regressed them).
//   STG=1: DMA ring, KSTEP=32, NBUF x 16 KB, counted vmcnt, 32 KB @ NBUF=2
//          -> 4 blocks/CU with OCC=4. scores (r5/r6/r7: 98.9-100.4 us).
//   STG=2: DMA double-buffer, KSTEP=64, 32-MFMA phases, vmcnt(8), 64 KB.
//          gemm3 (~95 us).
// Session findings (r0-r10):
//   - counted vmcnt (no vmcnt(0) in main loop) is required for any DMA
//     pipeline (r2: __syncthreads drains the prefetch);
//   - phase granularity (32-MFMA phases) > pipeline depth (r5/r6);
//   - direct-from-global fragments = exposed latency (r8: MfmaUtil 10%);
//   - 8-phase 256² port regressed (r10: 25% MfmaUtil, 1 blk/CU, 128
//     scalar stores/thread in epilogue -> +83 MB write amplification);
//   - all three GEMMs sit at the ~690 TF 2-phase structural plateau,
//     NOT BW-bound (1.9-2.4 of 6.3 TB/s) -> fp8-S16 would not pay.
//   DMA-path LDS: linear [128][32]/subtile; XOR slot swizzle on the GLOBAL
//   source (slot=(l&3)^((l>>3)&3)) + matching ds_read slot
//   (quad^((lrow>>1)&3)) — 0 bank conflicts (r2-measured).
// ---------------------------------------------------------------------------

#define LDT 40    // padded LDS row (f16 elems) per 32-k subtile (STG=0)
#define SUB 5120  // 128*LDT elems per subtile (STG=0)

typedef _Float16 f16x8 __attribute__((ext_vector_type(8)));
typedef float f32x4 __attribute__((ext_vector_type(4)));

__device__ __forceinline__ void async16(const _Float16* g, _Float16* l)
{
  __builtin_amdgcn_global_load_lds(
      (const __attribute__((address_space(1))) void*)g,
      (__attribute__((address_space(3))) void*)l, 16, 0, 0);
}

#define WVM(N) asm volatile("s_waitcnt vmcnt(" #N ")" ::: "memory")

// ASRC: 0 = plain A; 1 = A scaled by fs16[z][i0>>7][k] (gemm3)
// EPI:  1 = fp16 out + bias by col (bias0 j<512, bias1 else)  [projQK]
//       2 = fp16 out + bias by row (bias0)                     [projV]
//       3 = fp32 out = xadd[o] + alpha*acc                     [gemm3]
//       4 = fused scores: tile col stats -> pmax/psum, S~ fp16  [scores]
// NSUB: subtiles per phase (STG=0/2) or NBUF ring buffers (STG=1)
// OCC:  min waves/EU for __launch_bounds__ (4 => 4 blocks/CU of 256 thr)
template <int ASRC, int EPI, int NSUB, int STG, int OCC>
__global__ void __launch_bounds__(256, OCC) gemm_f16(
    const _Float16* __restrict__ Ap, long lda, long zsa,
    const _Float16* __restrict__ Bp, long ldb, long zsb,
    int kslice,
    const _Float16* __restrict__ fs16, long zsl,
    float* __restrict__ outF, _Float16* __restrict__ outH, long ldc, long zso,
    const float* __restrict__ bias0, const float* __restrict__ bias1,
    const float* __restrict__ xadd,
    float* __restrict__ pmax, float* __restrict__ psum, long zsp,
    float alpha)
{
  constexpr int SMEM_E = (STG == 1) ? (NSUB * 8192 + (ASRC == 1 ? 4096 : 0))
                       : (STG == 2) ? (4 * NSUB * 4096)
                                    : (2 * NSUB * SUB);
  __shared__ _Float16 smem[SMEM_E];

  const int z = blockIdx.z;
  const long i0 = (long)blockIdx.x * 128;
  const long j0 = (long)blockIdx.y * 128;
  const int t = (int)threadIdx.x;
  const int lane = t & 63;
  const int wv = t >> 6;
  const int quad = lane >> 4;
  const int lrow = lane & 15;
  const int wm = (wv & 1) << 6;
  const int wn = (wv >> 1) << 6;

  f32x4 acc[4][4];
  const f32x4 fz = {0.f, 0.f, 0.f, 0.f};
#pragma unroll
  for (int a = 0; a < 4; a++)
#pragma unroll
    for (int b = 0; b < 4; b++) acc[a][b] = fz;

  if constexpr (STG == 0) {
    // ---------- reg-staged path (coalesced lane map), 2-barrier ----------
    const int r0 = t >> 2;
    const int s0 = (t & 3) << 3;

    const _Float16* gA0 = Ap + z * zsa + (i0 + r0) * lda + s0;
    const _Float16* gA1 = gA0 + 64 * lda;
    const _Float16* gB0 = Bp + z * zsb + (j0 + r0) * ldb + s0;
    const _Float16* gB1 = gB0 + 64 * ldb;
    const int la0 = r0 * LDT + s0;
    const int la1 = (r0 + 64) * LDT + s0;

    for (int kk = 0; kk < kslice; kk += 32 * NSUB) {
      f16x8 va[NSUB][2], vb[NSUB][2];
#pragma unroll
      for (int s = 0; s < NSUB; s++) {
        va[s][0] = *(const f16x8*)(gA0 + kk + 32 * s);
        va[s][1] = *(const f16x8*)(gA1 + kk + 32 * s);
        vb[s][0] = *(const f16x8*)(gB0 + kk + 32 * s);
        vb[s][1] = *(const f16x8*)(gB1 + kk + 32 * s);
      }
      __syncthreads();
#pragma unroll
      for (int s = 0; s < NSUB; s++) {
        *(f16x8*)&smem[s * SUB + la0] = va[s][0];
        *(f16x8*)&smem[s * SUB + la1] = va[s][1];
        *(f16x8*)&smem[(NSUB + s) * SUB + la0] = vb[s][0];
        *(f16x8*)&smem[(NSUB + s) * SUB + la1] = vb[s][1];
      }
      __syncthreads();

#pragma unroll
      for (int h = 0; h < NSUB; h++) {
        const _Float16* pA = smem + h * SUB;
        const _Float16* pB = smem + (NSUB + h) * SUB;
        f16x8 fa[4], fb[4];
#pragma unroll
        for (int f = 0; f < 4; f++) {
          fa[f] = *(const f16x8*)&pA[(wm + f * 16 + lrow) * LDT + quad * 8];
          fb[f] = *(const f16x8*)&pB[(wn + f * 16 + lrow) * LDT + quad * 8];
        }
#pragma unroll
        for (int fm = 0; fm < 4; fm++)
#pragma unroll
          for (int fn = 0; fn < 4; fn++)
            acc[fm][fn] = __builtin_amdgcn_mfma_f32_16x16x32_f16(fa[fm], fb[fn], acc[fm][fn], 0, 0, 0);
      }
    }
  } else if constexpr (STG == 1) {
    // ---- DMA ring (KSTEP=32, NBUF=NSUB), counted vmcnt ----
    const int crow = lane >> 2;                               // row in 16-row chunk
    const int ks8 = (((lane & 3) ^ ((lane >> 3) & 3)) << 3);  // inverse-swizzled k slot

    // wave wv stages rows 16wv..+15 and 64+16wv..+15 of A and B subtiles
    const _Float16* gAc0 = Ap + z * zsa + (i0 + 16 * wv + crow) * lda + ks8;
    const _Float16* gAc1 = gAc0 + 64 * lda;
    const _Float16* gBc0 = Bp + z * zsb + (j0 + 16 * wv + crow) * ldb + ks8;
    const _Float16* gBc1 = gBc0 + 64 * ldb;

    // swizzled read slot: k-slice quad*8 sits at slot quad^((lrow>>1)&3)
    const int qs = ((quad ^ ((lrow >> 1) & 3)) << 3);

    auto stage = [&](int buf, int kk2) {
      _Float16* base = smem + buf * 8192;
      async16(gAc0 + kk2, base + wv * 512);
      async16(gAc1 + kk2, base + 2048 + wv * 512);
      async16(gBc0 + kk2, base + 4096 + wv * 512);
      async16(gBc1 + kk2, base + 6144 + wv * 512);
    };

    _Float16* fsL = nullptr;
    if constexpr (ASRC == 1) {
      fsL = smem + NSUB * 8192;
      const _Float16* fsrc = fs16 + z * zsl + (long)blockIdx.x * 4096;
      *(f16x8*)&fsL[t * 16] = *(const f16x8*)&fsrc[t * 16];
      *(f16x8*)&fsL[t * 16 + 8] = *(const f16x8*)&fsrc[t * 16 + 8];
    }
    stage(0, 0);
    if constexpr (NSUB == 4) { stage(1, 32); stage(2, 64); }
    if constexpr (ASRC == 1)
      asm volatile("s_waitcnt lgkmcnt(0)" ::: "memory");
    __builtin_amdgcn_s_barrier();

    int ib = 0;
    for (int kk = 0; kk < kslice; kk += 32, ++ib) {
      const int rem = kslice - kk;  // uniform scalar branches
      if constexpr (NSUB == 4) {
        if (rem > 96) { stage((ib + 3) & 3, kk + 96); WVM(12); }
        else if (rem > 64) { WVM(8); }
        else if (rem > 32) { WVM(4); }
        else { WVM(0); }
      } else {
        if (rem > 32) { stage((ib + 1) & 1, kk + 32); WVM(4); }
        else { WVM(0); }
      }
      __builtin_amdgcn_s_barrier();  // all waves' buf[cur] landed

      const int cur = ib & (NSUB - 1);
      const _Float16* pA = smem + cur * 8192;
      const _Float16* pB = pA + 4096;
      f16x8 fa[4], fb[4];
#pragma unroll
      for (int f = 0; f < 4; f++) {
        fa[f] = *(const f16x8*)&pA[(wm + f * 16 + lrow) * 32 + qs];
        fb[f] = *(const f16x8*)&pB[(wn + f * 16 + lrow) * 32 + qs];
      }
      if constexpr (ASRC == 1) {
        const f16x8 fsv = *(const f16x8*)&fsL[kk + quad * 8];  // broadcast
#pragma unroll
        for (int f = 0; f < 4; f++) fa[f] = fa[f] * fsv;
      }
#pragma unroll
      for (int fm = 0; fm < 4; fm++)
#pragma unroll
        for (int fn = 0; fn < 4; fn++)
          acc[fm][fn] = __builtin_amdgcn_mfma_f32_16x16x32_f16(fa[fm], fb[fn], acc[fm][fn], 0, 0, 0);

      __builtin_amdgcn_s_barrier();  // reads done before buf restaged
    }
  } else {
    // ---- STG=2: DMA dbuf, KSTEP=64, 32-MFMA phases, vmcnt(8) ----
    constexpr int KSTEP = 32 * NSUB;
    constexpr int BUFE = 2 * NSUB * 4096;  // f16 elems per buffer (A+B)
    const int crow = lane >> 2;
    const int ks8 = (((lane & 3) ^ ((lane >> 3) & 3)) << 3);

    const _Float16* gAc0 = Ap + z * zsa + (i0 + 16 * wv + crow) * lda + ks8;
    const _Float16* gAc1 = gAc0 + 64 * lda;
    const _Float16* gBc0 = Bp + z * zsb + (j0 + 16 * wv + crow) * ldb + ks8;
    const _Float16* gBc1 = gBc0 + 64 * ldb;
    _Float16* ldsC0 = smem + wv * 512;        // chunk wv dest (wave-uniform)
    _Float16* ldsC1 = smem + (wv + 4) * 512;  // chunk wv+4 dest

    const _Float16* fsZq = nullptr;
    if constexpr (ASRC == 1)
      fsZq = fs16 + z * zsl + (long)blockIdx.x * 4096 + quad * 8;

    const int qs = ((quad ^ ((lrow >> 1) & 3)) << 3);

    auto stage = [&](int buf, int kk) {
#pragma unroll
      for (int s = 0; s < NSUB; s++) {
        const int ab = buf * BUFE + s * 4096;
        const int bb = buf * BUFE + (NSUB + s) * 4096;
        async16(gAc0 + kk + 32 * s, ldsC0 + ab);
        async16(gAc1 + kk + 32 * s, ldsC1 + ab);
        async16(gBc0 + kk + 32 * s, ldsC0 + bb);
        async16(gBc1 + kk + 32 * s, ldsC1 + bb);
      }
    };

    stage(0, 0);  // 8 DMA in flight; no drain — counted in iter 0's vmcnt(8)
    int cur = 0;
    for (int kk = 0; kk < kslice; kk += KSTEP) {
      f16x8 fsv[NSUB];
      if constexpr (ASRC == 1) {
#pragma unroll
        for (int h = 0; h < NSUB; h++)
          fsv[h] = *(const f16x8*)(fsZq + kk + 32 * h);
      }
      if (kk + KSTEP < kslice) {
        stage(cur ^ 1, kk + KSTEP);  // prefetch: stays in flight across barriers
        WVM(8);                      // buf[cur]'s 8 loads (issued last iter) landed
      } else {
        WVM(0);                      // last iter: no prefetch behind, drain all
      }
      __builtin_amdgcn_s_barrier();

#pragma unroll
      for (int h = 0; h < NSUB; h++) {
        const _Float16* pA = smem + cur * BUFE + h * 4096;
        const _Float16* pB = smem + cur * BUFE + (NSUB + h) * 4096;
        f16x8 fa[4], fb[4];
#pragma unroll
        for (int f = 0; f < 4; f++) {
          fa[f] = *(const f16x8*)&pA[(wm + f * 16 + lrow) * 32 + qs];
          fb[f] = *(const f16x8*)&pB[(wn + f * 16 + lrow) * 32 + qs];
        }
        if constexpr (ASRC == 1) {
#pragma unroll
          for (int f = 0; f < 4; f++) fa[f] = fa[f] * fsv[h];
        }
#pragma unroll
        for (int fm = 0; fm < 4; fm++)
#pragma unroll
          for (int fn = 0; fn < 4; fn++)
            acc[fm][fn] = __builtin_amdgcn_mfma_f32_16x16x32_f16(fa[fm], fb[fn], acc[fm][fn], 0, 0, 0);
      }
      __builtin_amdgcn_s_barrier();  // reads done before buf restaged
      cur ^= 1;
    }
  }

  // D frag: col(j) = lane&15 (+wn+fn*16), row(i) = quad*4 + reg (+wm+fm*16)
  const long obase = (long)z * zso;

  if constexpr (EPI == 1 || EPI == 2) {
#pragma unroll
    for (int fm = 0; fm < 4; fm++) {
      const long gi0 = i0 + wm + fm * 16 + quad * 4;
#pragma unroll
      for (int fn = 0; fn < 4; fn++) {
        const long gj = j0 + wn + fn * 16 + lrow;
        float badd = 0.f;
        if constexpr (EPI == 1) badd = (gj < 512) ? bias0[gj] : bias1[gj - 512];
#pragma unroll
        for (int r = 0; r < 4; r++) {
          float v = acc[fm][fn][r];
          if constexpr (EPI == 1) v += badd;
          else v += bias0[gi0 + r];
          outH[obase + (gi0 + r) * ldc + gj] = (_Float16)v;
        }
      }
    }
  } else if constexpr (EPI == 3) {
#pragma unroll
    for (int fm = 0; fm < 4; fm++) {
      const long gi0 = i0 + wm + fm * 16 + quad * 4;
#pragma unroll
      for (int fn = 0; fn < 4; fn++) {
        const long gj = j0 + wn + fn * 16 + lrow;
#pragma unroll
        for (int r = 0; r < 4; r++) {
          const long o = obase + (gi0 + r) * ldc + gj;
          outF[o] = fmaf(alpha, acc[fm][fn][r], xadd[o]);
        }
      }
    }
  } else {  // EPI == 4: single-exp fused scores epilogue
    __syncthreads();  // done with K-loop LDS
    float* Ls = (float*)smem;
    // LDS float layout: [0,1024) partials (max, then reused for sums)
    //                   [1024,1280) half-maxes, [1280,1408) Mcol
    // stage 1: per-lane per-column-group MAX only (no exp)
#pragma unroll
    for (int fn = 0; fn < 4; fn++) {
      float mx = -3.4e38f;
#pragma unroll
      for (int fm = 0; fm < 4; fm++)
#pragma unroll
        for (int r = 0; r < 4; r++) mx = fmaxf(mx, acc[fm][fn][r]);
      Ls[(wv * 4 + quad) * 64 + fn * 16 + lrow] = mx;
    }
    __syncthreads();
    // stage 2: combine 4 quads -> per (row-half h, col c) max
    {
      const int c = t & 127;
      const int h = t >> 7;
      const int wvv = ((c >> 6) << 1) + h;
      const int wc = c & 63;
      float M = -3.4e38f;
#pragma unroll
      for (int q = 0; q < 4; q++) M = fmaxf(M, Ls[(wvv * 4 + q) * 64 + wc]);
      Ls[1024 + h * 128 + c] = M;
    }
    __syncthreads();
    // stage 3: column max; store pmax; park Mcol in LDS
    if (t < 128) {
      float Mcol = fmaxf(Ls[1024 + t], Ls[1152 + t]);
      pmax[z * zsp + (long)blockIdx.x * 4096 + j0 + t] = Mcol;
      Ls[1280 + t] = Mcol;
    }
    __syncthreads();
    // stage 4: single exp pass — store S~ AND accumulate column partial sums
#pragma unroll
    for (int fn = 0; fn < 4; fn++) {
      const int colc = wn + fn * 16 + lrow;
      const float Mcol = Ls[1280 + colc];
      const long gj = j0 + colc;
      float sm = 0.f;
#pragma unroll
      for (int fm = 0; fm < 4; fm++) {
        const long gi0 = i0 + wm + fm * 16 + quad * 4;
#pragma unroll
        for (int r = 0; r < 4; r++) {
          float e = __expf(acc[fm][fn][r] - Mcol);
          sm += e;
          outH[obase + (gi0 + r) * ldc + gj] = (_Float16)e;
        }
      }
      Ls[(wv * 4 + quad) * 64 + fn * 16 + lrow] = sm;  // reuse partial region
    }
    __syncthreads();
    // stage 5: pure-add reduce of 8 partials per column -> psum
    if (t < 128) {
      const int wc = t & 63;
      const int ch = t >> 6;
      float s = 0.f;
#pragma unroll
      for (int h = 0; h < 2; h++) {
        const int wvv = (ch << 1) + h;
#pragma unroll
        for (int q = 0; q < 4; q++) s += Ls[(wvv * 4 + q) * 64 + wc];
      }
      psum[z * zsp + (long)blockIdx.x * 4096 + j0 + t] = s;
    }
  }
}

__global__ void convert_weights(const float* __restrict__ Wq, const float* __restrict__ Wk,
                                const float* __restrict__ Wv,
                                _Float16* __restrict__ WQK, _Float16* __restrict__ Wv16)
{
  int idx = blockIdx.x * 256 + threadIdx.x;  // 0..786431
  if (idx < 524288)
    WQK[idx] = (_Float16)((idx < 262144) ? Wq[idx] : Wk[idx - 262144]);
  else
    Wv16[idx - 524288] = (_Float16)Wv[idx - 524288];
}

// x [b][c][n] fp32 -> xT [b][n][c] fp16
__global__ void transpose_x(const float* __restrict__ x, _Float16* __restrict__ xT)
{
  __shared__ float tile[32][33];
  const int b = blockIdx.z;
  const int n0 = blockIdx.x * 32;
  const int c0 = blockIdx.y * 32;
  const int tx = threadIdx.x;
  const int ty = threadIdx.y;
  const float* xb = x + (long)b * 2097152;
#pragma unroll
  for (int k = 0; k < 4; k++)
    tile[ty + k * 8][tx] = xb[(long)(c0 + ty + k * 8) * 4096 + n0 + tx];
  __syncthreads();
  _Float16* xTb = xT + (long)b * 2097152;
#pragma unroll
  for (int k = 0; k < 4; k++)
    xTb[(long)(n0 + ty + k * 8) * 512 + c0 + tx] = (_Float16)tile[tx][ty + k * 8];
}

// fused: lse[z][m] from 32 tile partials, then fs16[z][tile][m] = exp(pmax-lse)
__global__ void stats_scale(const float* __restrict__ pmax, const float* __restrict__ psum,
                            _Float16* __restrict__ fs16)
{
  const int idx = blockIdx.x * 256 + threadIdx.x;  // grid 64: z*4096+m
  const int z = idx >> 12;
  const int m = idx & 4095;
  const float* pm = pmax + (long)z * 131072 + m;
  const float* ps = psum + (long)z * 131072 + m;
  float M = -3.4e38f, S = 0.f;
  for (int i = 0; i < 32; i++) {
    float m2 = pm[(long)i * 4096], s2 = ps[(long)i * 4096];
    float nm = fmaxf(M, m2);
    S = S * __expf(M - nm) + s2 * __expf(m2 - nm);
    M = nm;
  }
  const float lse = M + __logf(S);
  _Float16* fo = fs16 + (long)z * 131072 + m;
  for (int i = 0; i < 32; i++)
    fo[(long)i * 4096] = (_Float16)__expf(pm[(long)i * 4096] - lse);
}

extern "C" void kernel_launch(void* const* d_in, const int* in_sizes, int n_in,
                              void* d_out, int out_size, void* d_ws, size_t ws_size,
                              hipStream_t stream)
{
  const float* x  = (const float*)d_in[0];
  const float* Wq = (const float*)d_in[1];
  const float* bq = (const float*)d_in[2];
  const float* Wk = (const float*)d_in[3];
  const float* bk = (const float*)d_in[4];
  const float* Wv = (const float*)d_in[5];
  const float* bv = (const float*)d_in[6];
  float* out = (float*)d_out;

  char* w = (char*)d_ws;
  _Float16* WQK   = (_Float16*)(w + 0);          //  1,048,576
  _Float16* Wv16  = (_Float16*)(w + 1048576);    //    524,288
  _Float16* xT    = (_Float16*)(w + 1572864);    // 16,777,216
  _Float16* QK    = (_Float16*)(w + 18350080);   // 33,554,432
  _Float16* Vt    = (_Float16*)(w + 51904512);   // 16,777,216
  float*    pmaxB = (float*)   (w + 68747264);   //  2,097,152
  float*    psumB = (float*)   (w + 70844416);   //  2,097,152
  _Float16* fs16  = (_Float16*)(w + 72941568);   //  1,048,576 = [z][32][4096] fp16
  _Float16* S16   = (_Float16*)(w + 75038720);   // 134,217,728
  // total 209,256,448 B

  convert_weights<<<3072, 256, 0, stream>>>(Wq, Wk, Wv, WQK, Wv16);
  transpose_x<<<dim3(128, 16, 4), dim3(32, 8), 0, stream>>>(x, xT);

  // projQK (STG=0, proven): QK[z][n][j], j<512 Q(+bq) else K(+bk)
  gemm_f16<0, 1, 2, 0, 2><<<dim3(32, 8, 4), 256, 0, stream>>>(
      xT, 512, 2097152L, WQK, 512, 0L, 512, nullptr, 0L,
      nullptr, QK, 1024, 4194304L, bq, bk, nullptr, nullptr, nullptr, 0L, 0.f);
  // projV (STG=0, proven): Vt[z][c][m] fp16 (+bv by row)
  gemm_f16<0, 2, 2, 0, 2><<<dim3(4, 32, 4), 256, 0, stream>>>(
      Wv16, 512, 0L, xT, 512, 2097152L, 512, nullptr, 0L,
      nullptr, Vt, 4096, 2097152L, bv, nullptr, nullptr, nullptr, nullptr, 0L, 0.f);
  // scores (STG=1 ring, NBUF=2, 32 KB, 4 blocks/CU — measured 98.9-100.4):
  gemm_f16<0, 4, 2, 1, 4><<<dim3(32, 32, 4), 256, 0, stream>>>(
      QK, 1024, 4194304L, QK + 512, 1024, 4194304L, 512, nullptr, 0L,
      nullptr, S16, 4096, 16777216L, nullptr, nullptr, nullptr,
      pmaxB, psumB, 131072L, 0.f);
  stats_scale<<<64, 256, 0, stream>>>(pmaxB, psumB, fs16);
  // gemm3 (STG=2 dbuf KSTEP=64, vmcnt(8), 64 KB — measured ~95):
  // out = x.flat + 0.1*(S~*fs16)·Vt^T
  gemm_f16<1, 3, 2, 2, 2><<<dim3(32, 4, 4), 256, 0, stream>>>(
      S16, 4096, 16777216L, Vt, 4096, 2097152L, 4096, fs16, 131072L,
      out, nullptr, 512, 2097152L, nullptr, nullptr, x, nullptr, nullptr, 0L, 0.1f);
}